// Round 7
// baseline (193.121 us; speedup 1.0000x reference)
//
#include <hip/hip_runtime.h>
#include <hip/hip_bf16.h>

#define N 8192
#define D 768
#define TEMP_INV 20.0f
#define NTILES 2080   // 64x64 tile-grid upper triangle incl. diagonal

typedef __attribute__((ext_vector_type(4))) float f32x4;
typedef __attribute__((ext_vector_type(4))) int i32x4;
typedef __attribute__((ext_vector_type(8))) int i32x8;

#define SCALE1 0x7F7F7F7F  // e8m0 = 127 in all 4 bytes -> scale 1.0

// Workspace layout (floats):
//   [0,   N)     rowsum   (zeroed by norm_kernel)
//   [N,  2N)     pos      (fully written by sim_kernel diag tiles)
//   [2N, 2N+16)  pad
//   [2N+16, ...) xn fp8-e4m3 [N][768] bytes

// ---------------------------------------------------------------------------
// Kernel 1: row L2-normalize fp32 -> fp8 e4m3. One row per wave (4 rows/block).
__global__ __launch_bounds__(256) void norm_kernel(
    const float* __restrict__ x, unsigned char* __restrict__ xn,
    float* __restrict__ rowsum) {
  int t = threadIdx.x, w = t >> 6, lane = t & 63;
  int row = blockIdx.x * 4 + w;
  const float4* xr = (const float4*)(x + (size_t)row * D);
  float4 v[3];
  v[0] = xr[lane];
  v[1] = xr[lane + 64];
  v[2] = xr[lane + 128];
  float ss = 0.0f;
#pragma unroll
  for (int i = 0; i < 3; ++i)
    ss += v[i].x * v[i].x + v[i].y * v[i].y + v[i].z * v[i].z + v[i].w * v[i].w;
#pragma unroll
  for (int m = 32; m; m >>= 1) ss += __shfl_xor(ss, m);
  float inv = 1.0f / fmaxf(sqrtf(ss), 1e-8f);
  unsigned int* xo = (unsigned int*)(xn + (size_t)row * D);
#pragma unroll
  for (int i = 0; i < 3; ++i) {
    int p = __builtin_amdgcn_cvt_pk_fp8_f32(v[i].x * inv, v[i].y * inv, 0, false);
    p = __builtin_amdgcn_cvt_pk_fp8_f32(v[i].z * inv, v[i].w * inv, p, true);
    xo[lane + 64 * i] = p;
  }
  if (t < 4) rowsum[blockIdx.x * 4 + t] = 0.0f;
}

// ---------------------------------------------------------------------------
// Kernel 2: upper-triangle 128x128 tiles of S = Xn * Xn^T via MX-scaled fp8
// MFMA (K=128, scales=1.0 -> plain fp8 GEMM at 2x non-scaled rate).
//
// NO LDS: fragment layout (row = lane&15, k = q*32..+31, 16B-aligned) is
// directly loadable with global_load_dwordx4 -> no barriers, no vmcnt(0)
// drain; the glds ~11 B/cyc/CU staging wall (rounds 2-6) is bypassed and
// loads pipeline against MFMA with fine-grained vmcnt.
//
// XCD-locality schedule: tiles enumerated supertile-major (8x8-tile
// supertiles, 16-panel working set = 1.5 MB < 4 MB per-XCD L2); global
// position p = 260*(blockIdx%8) + blockIdx/8 gives each XCD one contiguous
// 260-tile chunk (blockIdx%8 == XCD id, round-robin dispatch).
__global__ __launch_bounds__(256, 2) void sim_kernel(
    const unsigned char* __restrict__ xn, float* __restrict__ rowsum,
    float* __restrict__ pos) {
  // ---- tile decode: blockIdx -> XCD-chunk position -> supertile -> (bi,bj)
  static const short stbase[37] = {
      0, 36, 100, 164, 228, 292, 356, 420,
      484, 520, 584, 648, 712, 776, 840,
      904, 940, 1004, 1068, 1132, 1196,
      1260, 1296, 1360, 1424, 1488,
      1552, 1588, 1652, 1716,
      1780, 1816, 1880,
      1944, 1980,
      2044, 2080};
  static const char sti[36] = {0,0,0,0,0,0,0,0, 1,1,1,1,1,1,1, 2,2,2,2,2,2,
                               3,3,3,3,3, 4,4,4,4, 5,5,5, 6,6, 7};
  static const char stj[36] = {0,1,2,3,4,5,6,7, 1,2,3,4,5,6,7, 2,3,4,5,6,7,
                               3,4,5,6,7, 4,5,6,7, 5,6,7, 6,7, 7};
  int b = blockIdx.x;
  int p = 260 * (b & 7) + (b >> 3);
  int s = 0;
  while ((int)stbase[s + 1] <= p) ++s;
  int wofs = p - stbase[s];
  int SI = sti[s], SJ = stj[s];
  int bi, bj;
  if (SI == SJ) {  // diagonal supertile: triangular 8x8, counts 8,7,...,1
    int di = 0, cum = 0;
    while (wofs >= cum + (8 - di)) { cum += 8 - di; ++di; }
    bi = SI * 8 + di;
    bj = SI * 8 + di + (wofs - cum);
  } else {
    bi = SI * 8 + (wofs >> 3);
    bj = SJ * 8 + (wofs & 7);
  }

  int t = threadIdx.x;
  int w = t >> 6, lane = t & 63;
  int q = lane >> 4, cl = lane & 15;
  int wm = w >> 1, wn = w & 1;

  f32x4 acc[4][4] = {};

  // per-lane fragment base addresses: A row (bi*128 + wm*64 + m*16 + cl),
  // bytes kc*128 + q*32 .. +31  (16B-aligned: 768 = 48*16)
  const unsigned char* Abase = xn + (size_t)(bi * 128 + wm * 64 + cl) * D + q * 32;
  const unsigned char* Bbase = xn + (size_t)(bj * 128 + wn * 64 + cl) * D + q * 32;

  union Frag { i32x8 v8; struct { i32x4 lo, hi; } pr; };

#pragma unroll
  for (int kc = 0; kc < 6; ++kc) {
    Frag a[4], bb[4];
#pragma unroll
    for (int m = 0; m < 4; ++m) {
      const i32x4* pA = (const i32x4*)(Abase + (size_t)(m * 16) * D + kc * 128);
      a[m].pr.lo = pA[0];
      a[m].pr.hi = pA[1];
    }
#pragma unroll
    for (int n = 0; n < 4; ++n) {
      const i32x4* pB = (const i32x4*)(Bbase + (size_t)(n * 16) * D + kc * 128);
      bb[n].pr.lo = pB[0];
      bb[n].pr.hi = pB[1];
    }
#pragma unroll
    for (int m = 0; m < 4; ++m)
#pragma unroll
      for (int n = 0; n < 4; ++n)
        acc[m][n] = __builtin_amdgcn_mfma_scale_f32_16x16x128_f8f6f4(
            a[m].v8, bb[n].v8, acc[m][n], 0, 0, 0, SCALE1, 0, SCALE1);
  }

  // Epilogue. C/D layout: col = lane&15, row = (lane>>4)*4 + reg (shape-det.).
  int gi0 = bi * 128 + wm * 64;
  int gj0 = bj * 128 + wn * 64;

  float rowp[4][4] = {};
  float colp[4] = {};

  if (bi == bj) {
#pragma unroll
    for (int m = 0; m < 4; ++m)
#pragma unroll
      for (int n = 0; n < 4; ++n)
#pragma unroll
        for (int r = 0; r < 4; ++r) {
          float sv = acc[m][n][r];
          int row = gi0 + m * 16 + q * 4 + r;
          int col = gj0 + n * 16 + cl;
          float e = __expf(TEMP_INV * sv - 20.0f);
          if (col == row) e = 0.0f;
          if (col == (row ^ 1)) pos[row] = TEMP_INV * sv;
          rowp[m][r] += e;
        }
  } else {
#pragma unroll
    for (int m = 0; m < 4; ++m)
#pragma unroll
      for (int n = 0; n < 4; ++n)
#pragma unroll
        for (int r = 0; r < 4; ++r) {
          float e = __expf(TEMP_INV * acc[m][n][r] - 20.0f);
          rowp[m][r] += e;
          colp[n] += e;
        }
  }

#pragma unroll
  for (int m = 0; m < 4; ++m)
#pragma unroll
    for (int r = 0; r < 4; ++r) {
      float v = rowp[m][r];
      v += __shfl_xor(v, 1);
      v += __shfl_xor(v, 2);
      v += __shfl_xor(v, 4);
      v += __shfl_xor(v, 8);
      if (cl == 0) atomicAdd(&rowsum[gi0 + m * 16 + q * 4 + r], v);
    }
  if (bi != bj) {
#pragma unroll
    for (int n = 0; n < 4; ++n) {
      float v = colp[n];
      v += __shfl_xor(v, 16);
      v += __shfl_xor(v, 32);
      if (q == 0) atomicAdd(&rowsum[gj0 + n * 16 + cl], v);
    }
  }
}

// ---------------------------------------------------------------------------
// Kernel 3: loss = mean_i (20 + log(rowsum[i]) - pos[i]); one 1024-thread block
__global__ __launch_bounds__(1024) void loss_kernel(
    const float* __restrict__ rowsum, const float* __restrict__ pos,
    float* __restrict__ out) {
  int t = threadIdx.x;
  const float4* r4 = (const float4*)rowsum;
  const float4* p4 = (const float4*)pos;
  float acc = 0.0f;
#pragma unroll
  for (int it = 0; it < 2; ++it) {
    int i = t + it * 1024;
    float4 r = r4[i], pp = p4[i];
    acc += 80.0f + __logf(r.x) + __logf(r.y) + __logf(r.z) + __logf(r.w)
           - pp.x - pp.y - pp.z - pp.w;
  }
#pragma unroll
  for (int m = 32; m; m >>= 1) acc += __shfl_xor(acc, m);
  __shared__ float wsum[16];
  if ((t & 63) == 0) wsum[t >> 6] = acc;
  __syncthreads();
  if (t == 0) {
    float tot = 0.0f;
#pragma unroll
    for (int i = 0; i < 16; ++i) tot += wsum[i];
    out[0] = tot / (float)N;
  }
}

extern "C" void kernel_launch(void* const* d_in, const int* in_sizes, int n_in,
                              void* d_out, int out_size, void* d_ws, size_t ws_size,
                              hipStream_t stream) {
  const float* x = (const float*)d_in[0];
  float* rowsum = (float*)d_ws;
  float* pos = rowsum + N;
  unsigned char* xn = (unsigned char*)(rowsum + 2 * N + 16);

  norm_kernel<<<N / 4, 256, 0, stream>>>(x, xn, rowsum);
  sim_kernel<<<NTILES, 256, 0, stream>>>(xn, rowsum, pos);
  loss_kernel<<<1, 1024, 0, stream>>>(rowsum, pos, (float*)d_out);
}

// Round 8
// 133.590 us; speedup vs baseline: 1.4456x; 1.4456x over previous
//
#include <hip/hip_runtime.h>
#include <hip/hip_bf16.h>

#define N 8192
#define D 768
#define TEMP_INV 20.0f
#define NTILES 2080   // 64x64 tile-grid upper triangle incl. diagonal

typedef __attribute__((ext_vector_type(4))) float f32x4;
typedef __attribute__((ext_vector_type(4))) int i32x4;
typedef __attribute__((ext_vector_type(8))) int i32x8;

#define SCALE1 0x7F7F7F7F  // e8m0 = 127 in all 4 bytes -> scale 1.0

// Workspace layout (floats):
//   [0,   N)     rowsum   (zeroed by norm_kernel)
//   [N,  2N)     pos      (fully written by sim_kernel diag tiles)
//   [2N, 2N+16)  pad
//   [2N+16, ...) xn fp8-e4m3, PRE-SHUFFLED fragment-major layout:
//     element (row, kbyte): panel p=row>>4, r=row&15, kc=kbyte>>7,
//     q=(kbyte>>5)&3, h=(kbyte>>4)&1, o=kbyte&15
//     addr = p*12288 + kc*2048 + h*1024 + (q*16+r)*16 + o
//     -> one MFMA fragment (panel,kc) = two contiguous 1024B blocks in
//        exact lane order (lane = q*16+cl): perfectly coalesced dwordx4.

// ---------------------------------------------------------------------------
// Kernel 1: row L2-normalize fp32 -> fp8 e4m3 in pre-shuffled layout.
// One block per 16-row panel; wave w handles rows 4w..4w+3; scatter through
// LDS, then one coalesced 12 KB panel copy to global.
__global__ __launch_bounds__(256) void norm_kernel(
    const float* __restrict__ x, unsigned char* __restrict__ xn,
    float* __restrict__ rowsum) {
  int t = threadIdx.x, w = t >> 6, lane = t & 63;
  int p = blockIdx.x;  // panel
  __shared__ unsigned int lds[3072];  // 12 KB panel staging
#pragma unroll
  for (int it = 0; it < 4; ++it) {
    int r = w * 4 + it;
    const float4* xr = (const float4*)(x + (size_t)(p * 16 + r) * D);
    float4 v[3];
    v[0] = xr[lane];
    v[1] = xr[lane + 64];
    v[2] = xr[lane + 128];
    float ss = 0.0f;
#pragma unroll
    for (int i = 0; i < 3; ++i)
      ss += v[i].x * v[i].x + v[i].y * v[i].y + v[i].z * v[i].z + v[i].w * v[i].w;
#pragma unroll
    for (int m = 32; m; m >>= 1) ss += __shfl_xor(ss, m);
    float inv = 1.0f / fmaxf(sqrtf(ss), 1e-8f);
#pragma unroll
    for (int i = 0; i < 3; ++i) {
      int pk = __builtin_amdgcn_cvt_pk_fp8_f32(v[i].x * inv, v[i].y * inv, 0, false);
      pk = __builtin_amdgcn_cvt_pk_fp8_f32(v[i].z * inv, v[i].w * inv, pk, true);
      int d = lane + 64 * i;  // dword index within row (0..191)
      int kc = d >> 5, dd = d & 31;
      int qq = dd >> 3, h = (dd >> 2) & 1, o4 = d & 3;
      lds[kc * 512 + h * 256 + (qq * 16 + r) * 4 + o4] = (unsigned int)pk;
    }
  }
  __syncthreads();
  const uint4* ls = (const uint4*)lds;
  uint4* dst = (uint4*)(xn + (size_t)p * 12288);
#pragma unroll
  for (int j = 0; j < 3; ++j) dst[t + 256 * j] = ls[t + 256 * j];
  if (t < 16) rowsum[p * 16 + t] = 0.0f;
}

// ---------------------------------------------------------------------------
// Kernel 2: upper-triangle 128x128 tiles of S = Xn * Xn^T via MX-scaled fp8
// MFMA (K=128, scales=1.0). NO LDS, NO barriers: pre-shuffled layout makes
// every fragment two dense coalesced global_load_dwordx4; explicit 2-deep
// register ping-pong pipeline (kc+1 loads issued before kc MFMAs).
//
// XCD-locality schedule: supertile-major enumeration (8x8-tile supertiles,
// 1.5 MB working set < 4 MB per-XCD L2); p = 260*(blockIdx%8) + blockIdx/8.
__global__ __launch_bounds__(256, 2) void sim_kernel(
    const unsigned char* __restrict__ xn, float* __restrict__ rowsum,
    float* __restrict__ pos) {
  static const short stbase[37] = {
      0, 36, 100, 164, 228, 292, 356, 420,
      484, 520, 584, 648, 712, 776, 840,
      904, 940, 1004, 1068, 1132, 1196,
      1260, 1296, 1360, 1424, 1488,
      1552, 1588, 1652, 1716,
      1780, 1816, 1880,
      1944, 1980,
      2044, 2080};
  static const char sti[36] = {0,0,0,0,0,0,0,0, 1,1,1,1,1,1,1, 2,2,2,2,2,2,
                               3,3,3,3,3, 4,4,4,4, 5,5,5, 6,6, 7};
  static const char stj[36] = {0,1,2,3,4,5,6,7, 1,2,3,4,5,6,7, 2,3,4,5,6,7,
                               3,4,5,6,7, 4,5,6,7, 5,6,7, 6,7, 7};
  int b = blockIdx.x;
  int pp = 260 * (b & 7) + (b >> 3);
  int s = 0;
  while ((int)stbase[s + 1] <= pp) ++s;
  int wofs = pp - stbase[s];
  int SI = sti[s], SJ = stj[s];
  int bi, bj;
  if (SI == SJ) {
    int di = 0, cum = 0;
    while (wofs >= cum + (8 - di)) { cum += 8 - di; ++di; }
    bi = SI * 8 + di;
    bj = SI * 8 + di + (wofs - cum);
  } else {
    bi = SI * 8 + (wofs >> 3);
    bj = SJ * 8 + (wofs & 7);
  }

  int t = threadIdx.x;
  int w = t >> 6, lane = t & 63;
  int q = lane >> 4, cl = lane & 15;
  int wm = w >> 1, wn = w & 1;

  f32x4 acc[4][4] = {};

  // fragment base: panel pa = bi*8 + wm*4 + m; block (pa,kc) at
  // pa*12288 + kc*2048; lane's 16B at +lane*16 (lo) / +1024+lane*16 (hi)
  const unsigned char* Abase = xn + (size_t)(bi * 8 + wm * 4) * 12288 + lane * 16;
  const unsigned char* Bbase = xn + (size_t)(bj * 8 + wn * 4) * 12288 + lane * 16;

  union Frag { i32x8 v8; struct { i32x4 lo, hi; } pr; };
  Frag a[2][4], bb[2][4];

#define LOAD_KC(buf, kc)                                                   \
  {                                                                        \
    _Pragma("unroll") for (int m = 0; m < 4; ++m) {                        \
      const unsigned char* pA = Abase + m * 12288 + (kc) * 2048;           \
      a[buf][m].pr.lo = *(const i32x4*)pA;                                 \
      a[buf][m].pr.hi = *(const i32x4*)(pA + 1024);                        \
    }                                                                      \
    _Pragma("unroll") for (int n = 0; n < 4; ++n) {                        \
      const unsigned char* pB = Bbase + n * 12288 + (kc) * 2048;           \
      bb[buf][n].pr.lo = *(const i32x4*)pB;                                \
      bb[buf][n].pr.hi = *(const i32x4*)(pB + 1024);                       \
    }                                                                      \
  }

  LOAD_KC(0, 0);
#pragma unroll
  for (int kc = 0; kc < 6; ++kc) {
    int cur = kc & 1;
    if (kc < 5) LOAD_KC(cur ^ 1, kc + 1);
#pragma unroll
    for (int m = 0; m < 4; ++m)
#pragma unroll
      for (int n = 0; n < 4; ++n)
        acc[m][n] = __builtin_amdgcn_mfma_scale_f32_16x16x128_f8f6f4(
            a[cur][m].v8, bb[cur][n].v8, acc[m][n], 0, 0, 0, SCALE1, 0, SCALE1);
  }
#undef LOAD_KC

  // Epilogue. C/D layout: col = lane&15, row = (lane>>4)*4 + reg (shape-det.).
  int gi0 = bi * 128 + wm * 64;
  int gj0 = bj * 128 + wn * 64;

  float rowp[4][4] = {};
  float colp[4] = {};

  if (bi == bj) {
#pragma unroll
    for (int m = 0; m < 4; ++m)
#pragma unroll
      for (int n = 0; n < 4; ++n)
#pragma unroll
        for (int r = 0; r < 4; ++r) {
          float sv = acc[m][n][r];
          int row = gi0 + m * 16 + q * 4 + r;
          int col = gj0 + n * 16 + cl;
          float e = __expf(TEMP_INV * sv - 20.0f);
          if (col == row) e = 0.0f;
          if (col == (row ^ 1)) pos[row] = TEMP_INV * sv;
          rowp[m][r] += e;
        }
  } else {
#pragma unroll
    for (int m = 0; m < 4; ++m)
#pragma unroll
      for (int n = 0; n < 4; ++n)
#pragma unroll
        for (int r = 0; r < 4; ++r) {
          float e = __expf(TEMP_INV * acc[m][n][r] - 20.0f);
          rowp[m][r] += e;
          colp[n] += e;
        }
  }

#pragma unroll
  for (int m = 0; m < 4; ++m)
#pragma unroll
    for (int r = 0; r < 4; ++r) {
      float v = rowp[m][r];
      v += __shfl_xor(v, 1);
      v += __shfl_xor(v, 2);
      v += __shfl_xor(v, 4);
      v += __shfl_xor(v, 8);
      if (cl == 0) atomicAdd(&rowsum[gi0 + m * 16 + q * 4 + r], v);
    }
  if (bi != bj) {
#pragma unroll
    for (int n = 0; n < 4; ++n) {
      float v = colp[n];
      v += __shfl_xor(v, 16);
      v += __shfl_xor(v, 32);
      if (q == 0) atomicAdd(&rowsum[gj0 + n * 16 + cl], v);
    }
  }
}

// ---------------------------------------------------------------------------
// Kernel 3: loss = mean_i (20 + log(rowsum[i]) - pos[i]); one 1024-thread block
__global__ __launch_bounds__(1024) void loss_kernel(
    const float* __restrict__ rowsum, const float* __restrict__ pos,
    float* __restrict__ out) {
  int t = threadIdx.x;
  const float4* r4 = (const float4*)rowsum;
  const float4* p4 = (const float4*)pos;
  float acc = 0.0f;
#pragma unroll
  for (int it = 0; it < 2; ++it) {
    int i = t + it * 1024;
    float4 r = r4[i], pv = p4[i];
    acc += 80.0f + __logf(r.x) + __logf(r.y) + __logf(r.z) + __logf(r.w)
           - pv.x - pv.y - pv.z - pv.w;
  }
#pragma unroll
  for (int m = 32; m; m >>= 1) acc += __shfl_xor(acc, m);
  __shared__ float wsum[16];
  if ((t & 63) == 0) wsum[t >> 6] = acc;
  __syncthreads();
  if (t == 0) {
    float tot = 0.0f;
#pragma unroll
    for (int i = 0; i < 16; ++i) tot += wsum[i];
    out[0] = tot / (float)N;
  }
}

extern "C" void kernel_launch(void* const* d_in, const int* in_sizes, int n_in,
                              void* d_out, int out_size, void* d_ws, size_t ws_size,
                              hipStream_t stream) {
  const float* x = (const float*)d_in[0];
  float* rowsum = (float*)d_ws;
  float* pos = rowsum + N;
  unsigned char* xn = (unsigned char*)(rowsum + 2 * N + 16);

  norm_kernel<<<N / 16, 256, 0, stream>>>(x, xn, rowsum);
  sim_kernel<<<NTILES, 256, 0, stream>>>(xn, rowsum, pos);
  loss_kernel<<<1, 1024, 0, stream>>>(rowsum, pos, (float*)d_out);
}

// Round 9
// 129.923 us; speedup vs baseline: 1.4864x; 1.0282x over previous
//
#include <hip/hip_runtime.h>
#include <hip/hip_bf16.h>

#define N 8192
#define D 768
#define TEMP_INV 20.0f
#define NTILES 2080   // 64x64 tile-grid upper triangle incl. diagonal

typedef __attribute__((ext_vector_type(4))) float f32x4;
typedef __attribute__((ext_vector_type(4))) int i32x4;
typedef __attribute__((ext_vector_type(8))) int i32x8;

#define SCALE1 0x7F7F7F7F  // e8m0 = 127 in all 4 bytes -> scale 1.0

// Workspace layout (floats):
//   [0,   N)     rowsum   (zeroed by norm_kernel)
//   [N,  2N)     pos      (fully written by sim_kernel diag tiles)
//   [2N, 2N+16)  pad
//   [2N+16, ...) xn fp8-e4m3, PRE-SHUFFLED fragment-major layout:
//     element (row, kbyte): panel p=row>>4, r=row&15, kc=kbyte>>7,
//     q=(kbyte>>5)&3, h=(kbyte>>4)&1, o=kbyte&15
//     addr = p*12288 + kc*2048 + h*1024 + (q*16+r)*16 + o
//     -> one MFMA fragment (panel,kc) = two contiguous 1024B blocks in
//        exact lane order (lane = q*16+cl): perfectly coalesced dwordx4.

// ---------------------------------------------------------------------------
// Kernel 1: row L2-normalize fp32 -> fp8 e4m3 in pre-shuffled layout.
__global__ __launch_bounds__(256) void norm_kernel(
    const float* __restrict__ x, unsigned char* __restrict__ xn,
    float* __restrict__ rowsum) {
  int t = threadIdx.x, w = t >> 6, lane = t & 63;
  int p = blockIdx.x;  // panel
  __shared__ unsigned int lds[3072];  // 12 KB panel staging
#pragma unroll
  for (int it = 0; it < 4; ++it) {
    int r = w * 4 + it;
    const float4* xr = (const float4*)(x + (size_t)(p * 16 + r) * D);
    float4 v[3];
    v[0] = xr[lane];
    v[1] = xr[lane + 64];
    v[2] = xr[lane + 128];
    float ss = 0.0f;
#pragma unroll
    for (int i = 0; i < 3; ++i)
      ss += v[i].x * v[i].x + v[i].y * v[i].y + v[i].z * v[i].z + v[i].w * v[i].w;
#pragma unroll
    for (int m = 32; m; m >>= 1) ss += __shfl_xor(ss, m);
    float inv = 1.0f / fmaxf(sqrtf(ss), 1e-8f);
#pragma unroll
    for (int i = 0; i < 3; ++i) {
      int pk = __builtin_amdgcn_cvt_pk_fp8_f32(v[i].x * inv, v[i].y * inv, 0, false);
      pk = __builtin_amdgcn_cvt_pk_fp8_f32(v[i].z * inv, v[i].w * inv, pk, true);
      int d = lane + 64 * i;  // dword index within row (0..191)
      int kc = d >> 5, dd = d & 31;
      int qq = dd >> 3, h = (dd >> 2) & 1, o4 = d & 3;
      lds[kc * 512 + h * 256 + (qq * 16 + r) * 4 + o4] = (unsigned int)pk;
    }
  }
  __syncthreads();
  const uint4* ls = (const uint4*)lds;
  uint4* dst = (uint4*)(xn + (size_t)p * 12288);
#pragma unroll
  for (int j = 0; j < 3; ++j) dst[t + 256 * j] = ls[t + 256 * j];
  if (t < 16) rowsum[p * 16 + t] = 0.0f;
}

// ---------------------------------------------------------------------------
// Kernel 2: upper-triangle 128x128 tiles of S = Xn * Xn^T via MX-scaled fp8
// MFMA (K=128, scales=1.0). NO LDS, NO barriers: pre-shuffled layout makes
// every fragment two dense coalesced global_load_dwordx4. Explicit 2-deep
// register ping-pong; __builtin_amdgcn_sched_barrier(0) pins the prefetch
// loads (kc+1) BEFORE the kc MFMA group so the compiler cannot re-serialize
// (round 8: VGPR=88 showed it collapsed the pipeline -> latency-bound).
//
// XCD-locality schedule: supertile-major enumeration (8x8-tile supertiles,
// 1.5 MB working set < 4 MB per-XCD L2); p = 260*(blockIdx%8) + blockIdx/8.
__global__ __launch_bounds__(256, 2) void sim_kernel(
    const unsigned char* __restrict__ xn, float* __restrict__ rowsum,
    float* __restrict__ pos) {
  static const short stbase[37] = {
      0, 36, 100, 164, 228, 292, 356, 420,
      484, 520, 584, 648, 712, 776, 840,
      904, 940, 1004, 1068, 1132, 1196,
      1260, 1296, 1360, 1424, 1488,
      1552, 1588, 1652, 1716,
      1780, 1816, 1880,
      1944, 1980,
      2044, 2080};
  static const char sti[36] = {0,0,0,0,0,0,0,0, 1,1,1,1,1,1,1, 2,2,2,2,2,2,
                               3,3,3,3,3, 4,4,4,4, 5,5,5, 6,6, 7};
  static const char stj[36] = {0,1,2,3,4,5,6,7, 1,2,3,4,5,6,7, 2,3,4,5,6,7,
                               3,4,5,6,7, 4,5,6,7, 5,6,7, 6,7, 7};
  int b = blockIdx.x;
  int pp = 260 * (b & 7) + (b >> 3);
  int s = 0;
  while ((int)stbase[s + 1] <= pp) ++s;
  int wofs = pp - stbase[s];
  int SI = sti[s], SJ = stj[s];
  int bi, bj;
  if (SI == SJ) {
    int di = 0, cum = 0;
    while (wofs >= cum + (8 - di)) { cum += 8 - di; ++di; }
    bi = SI * 8 + di;
    bj = SI * 8 + di + (wofs - cum);
  } else {
    bi = SI * 8 + (wofs >> 3);
    bj = SJ * 8 + (wofs & 7);
  }

  int t = threadIdx.x;
  int w = t >> 6, lane = t & 63;
  int q = lane >> 4, cl = lane & 15;
  int wm = w >> 1, wn = w & 1;

  f32x4 acc[4][4] = {};

  // fragment base: panel pa = bi*8 + wm*4 + m; block (pa,kc) at
  // pa*12288 + kc*2048; lane's 16B at +lane*16 (lo) / +1024+lane*16 (hi)
  const unsigned char* Abase = xn + (size_t)(bi * 8 + wm * 4) * 12288 + lane * 16;
  const unsigned char* Bbase = xn + (size_t)(bj * 8 + wn * 4) * 12288 + lane * 16;

  union Frag { i32x8 v8; struct { i32x4 lo, hi; } pr; };
  Frag a[2][4], bb[2][4];

#define LOAD_KC(buf, kc)                                                   \
  {                                                                        \
    _Pragma("unroll") for (int m = 0; m < 4; ++m) {                        \
      const unsigned char* pA = Abase + m * 12288 + (kc) * 2048;           \
      a[buf][m].pr.lo = *(const i32x4*)pA;                                 \
      a[buf][m].pr.hi = *(const i32x4*)(pA + 1024);                        \
    }                                                                      \
    _Pragma("unroll") for (int n = 0; n < 4; ++n) {                        \
      const unsigned char* pB = Bbase + n * 12288 + (kc) * 2048;           \
      bb[buf][n].pr.lo = *(const i32x4*)pB;                                \
      bb[buf][n].pr.hi = *(const i32x4*)(pB + 1024);                       \
    }                                                                      \
  }

  LOAD_KC(0, 0);
#pragma unroll
  for (int kc = 0; kc < 6; ++kc) {
    int cur = kc & 1;
    if (kc < 5) LOAD_KC(cur ^ 1, kc + 1);
    // Pin schedule: prefetch loads above, MFMA group below. Nothing crosses.
    __builtin_amdgcn_sched_barrier(0);
#pragma unroll
    for (int m = 0; m < 4; ++m)
#pragma unroll
      for (int n = 0; n < 4; ++n)
        acc[m][n] = __builtin_amdgcn_mfma_scale_f32_16x16x128_f8f6f4(
            a[cur][m].v8, bb[cur][n].v8, acc[m][n], 0, 0, 0, SCALE1, 0, SCALE1);
    __builtin_amdgcn_sched_barrier(0);
  }
#undef LOAD_KC

  // Epilogue. C/D layout: col = lane&15, row = (lane>>4)*4 + reg (shape-det.).
  int gi0 = bi * 128 + wm * 64;
  int gj0 = bj * 128 + wn * 64;

  float rowp[4][4] = {};
  float colp[4] = {};

  if (bi == bj) {
#pragma unroll
    for (int m = 0; m < 4; ++m)
#pragma unroll
      for (int n = 0; n < 4; ++n)
#pragma unroll
        for (int r = 0; r < 4; ++r) {
          float sv = acc[m][n][r];
          int row = gi0 + m * 16 + q * 4 + r;
          int col = gj0 + n * 16 + cl;
          float e = __expf(TEMP_INV * sv - 20.0f);
          if (col == row) e = 0.0f;
          if (col == (row ^ 1)) pos[row] = TEMP_INV * sv;
          rowp[m][r] += e;
        }
  } else {
#pragma unroll
    for (int m = 0; m < 4; ++m)
#pragma unroll
      for (int n = 0; n < 4; ++n)
#pragma unroll
        for (int r = 0; r < 4; ++r) {
          float e = __expf(TEMP_INV * acc[m][n][r] - 20.0f);
          rowp[m][r] += e;
          colp[n] += e;
        }
  }

#pragma unroll
  for (int m = 0; m < 4; ++m)
#pragma unroll
    for (int r = 0; r < 4; ++r) {
      float v = rowp[m][r];
      v += __shfl_xor(v, 1);
      v += __shfl_xor(v, 2);
      v += __shfl_xor(v, 4);
      v += __shfl_xor(v, 8);
      if (cl == 0) atomicAdd(&rowsum[gi0 + m * 16 + q * 4 + r], v);
    }
  if (bi != bj) {
#pragma unroll
    for (int n = 0; n < 4; ++n) {
      float v = colp[n];
      v += __shfl_xor(v, 16);
      v += __shfl_xor(v, 32);
      if (q == 0) atomicAdd(&rowsum[gj0 + n * 16 + cl], v);
    }
  }
}

// ---------------------------------------------------------------------------
// Kernel 3: loss = mean_i (20 + log(rowsum[i]) - pos[i]); one 1024-thread block
__global__ __launch_bounds__(1024) void loss_kernel(
    const float* __restrict__ rowsum, const float* __restrict__ pos,
    float* __restrict__ out) {
  int t = threadIdx.x;
  const float4* r4 = (const float4*)rowsum;
  const float4* p4 = (const float4*)pos;
  float acc = 0.0f;
#pragma unroll
  for (int it = 0; it < 2; ++it) {
    int i = t + it * 1024;
    float4 r = r4[i], pv = p4[i];
    acc += 80.0f + __logf(r.x) + __logf(r.y) + __logf(r.z) + __logf(r.w)
           - pv.x - pv.y - pv.z - pv.w;
  }
#pragma unroll
  for (int m = 32; m; m >>= 1) acc += __shfl_xor(acc, m);
  __shared__ float wsum[16];
  if ((t & 63) == 0) wsum[t >> 6] = acc;
  __syncthreads();
  if (t == 0) {
    float tot = 0.0f;
#pragma unroll
    for (int i = 0; i < 16; ++i) tot += wsum[i];
    out[0] = tot / (float)N;
  }
}

extern "C" void kernel_launch(void* const* d_in, const int* in_sizes, int n_in,
                              void* d_out, int out_size, void* d_ws, size_t ws_size,
                              hipStream_t stream) {
  const float* x = (const float*)d_in[0];
  float* rowsum = (float*)d_ws;
  float* pos = rowsum + N;
  unsigned char* xn = (unsigned char*)(rowsum + 2 * N + 16);

  norm_kernel<<<N / 16, 256, 0, stream>>>(x, xn, rowsum);
  sim_kernel<<<NTILES, 256, 0, stream>>>(xn, rowsum, pos);
  loss_kernel<<<1, 1024, 0, stream>>>(rowsum, pos, (float*)d_out);
}